// Round 1
// baseline (291.334 us; speedup 1.0000x reference)
//
#include <hip/hip_runtime.h>
#include <math.h>

#define Bn 64
#define In 2048
#define On 2048
#define Sn 10
#define Cn 512

#define OT 4            // o's per block
#define KT 64           // K tile
#define NP 48           // padded N: 40 dendrite + 4 synaptic + 4 zero
#define LROW 72         // padded row stride in bf16 elems (KT + 8)
#define NSTAGE (In / KT)

typedef short short8 __attribute__((ext_vector_type(8)));
typedef float f32x4 __attribute__((ext_vector_type(4)));
typedef unsigned short ushort4v __attribute__((ext_vector_type(4)));

__device__ __forceinline__ unsigned short f2bf(float f) {
    union { float f; unsigned u; } v; v.f = f;
    unsigned r = (v.u + 0x7FFFu + ((v.u >> 16) & 1u)) >> 16;  // RNE
    return (unsigned short)r;
}

// blocks 0..63: ctx_signal[b] = mean(context[b,:]); blocks 64..575: x -> bf16
__global__ void prep_kernel(const float* __restrict__ x,
                            const float* __restrict__ ctx,
                            float* __restrict__ ws_ctx,
                            unsigned short* __restrict__ ws_xbf) {
    const int b = blockIdx.x;
    const int t = threadIdx.x;
    if (b < Bn) {
        __shared__ float red[256];
        float s = ctx[b * Cn + t] + ctx[b * Cn + t + 256];
        red[t] = s;
        __syncthreads();
        for (int off = 128; off > 0; off >>= 1) {
            if (t < off) red[t] += red[t + off];
            __syncthreads();
        }
        if (t == 0) ws_ctx[b] = red[0] * (1.0f / (float)Cn);
    } else {
        int idx = (b - Bn) * 256 + t;
        ws_xbf[idx] = f2bf(x[idx]);
    }
}

__global__ __launch_bounds__(256, 2)
void main_kernel(const unsigned short* __restrict__ xbf,
                 const float* __restrict__ wgt,
                 const float* __restrict__ cst,
                 const float* __restrict__ seg,
                 const float* __restrict__ bias,
                 const float* __restrict__ aact,
                 const float* __restrict__ athr,
                 const float* __restrict__ gates,
                 const float* __restrict__ prn,
                 const float* __restrict__ ws_ctx,
                 float* __restrict__ out) {
    __shared__ __align__(16) unsigned short Alds[2][64 * LROW];
    __shared__ __align__(16) unsigned short Blds[2][NP * LROW];
    __shared__ float dsum[Bn][OT];
    __shared__ float ssum[Bn][OT];
    __shared__ float mastro[OT];

    const int t = threadIdx.x;
    const int o0 = blockIdx.x * OT;
    const int wave = t >> 6;
    const int lane = t & 63;
    const int l15 = lane & 15;
    const int q = lane >> 4;
    const float pthr = prn[0];

    // zero-init epilogue buffers (barriers in K-loop make this visible)
    ((float*)dsum)[t] = 0.0f;
    ((float*)ssum)[t] = 0.0f;

    // zero the pad rows 44..47 of both B buffers (never rewritten)
    for (int idx = t; idx < 4 * LROW; idx += 256) {
        Blds[0][44 * LROW + idx] = 0;
        Blds[1][44 * LROW + idx] = 0;
    }

    // mean_astro for this block's 4 outputs (threads 0..3)
    if (t < OT) {
        const int o = o0 + t;
        const float aa = aact[o], th = athr[o];
        float sum = 0.0f;
        for (int b2 = 0; b2 < Bn; ++b2) {
            float sg = 1.0f / (1.0f + expf(-ws_ctx[b2] * aa));
            if (sg > th) sum += sg;
        }
        mastro[t] = sum * (1.0f / (float)Bn);
    }

    // ---- staging register state ----
    const int s_o = t >> 6;          // one o per wave
    const int s_i = t & 63;
    const float* segp = seg + ((size_t)(o0 + s_o) * In + s_i) * Sn;
    const int xm0 = t >> 3;
    const int xk0 = (t & 7) * 8;
    const int xm1 = 32 + (t >> 3);
    const int w_o = t >> 4;          // valid only t<64
    const int w_k = (t & 15) * 4;

    float sreg[10];
    short8 xv0, xv1;
    f32x4 wv, cv;

    auto load_stage = [&](int i0) {
        const float* sp = segp + (size_t)i0 * Sn;
#pragma unroll
        for (int r2 = 0; r2 < 5; ++r2) {
            float2 tmp = *(const float2*)(sp + r2 * 2);
            sreg[2 * r2] = tmp.x;
            sreg[2 * r2 + 1] = tmp.y;
        }
        xv0 = *(const short8*)(xbf + xm0 * In + i0 + xk0);
        xv1 = *(const short8*)(xbf + xm1 * In + i0 + xk0);
        if (t < 64) {
            wv = *(const f32x4*)(wgt + (size_t)(o0 + w_o) * In + i0 + w_k);
            cv = *(const f32x4*)(cst + (size_t)(o0 + w_o) * In + i0 + w_k);
        }
    };

    auto store_stage = [&](int bb) {
        unsigned short* Bp = &Blds[bb][(s_o * 10) * LROW + s_i];
#pragma unroll
        for (int s = 0; s < 10; ++s) Bp[s * LROW] = f2bf(sreg[s]);
        *(short8*)&Alds[bb][xm0 * LROW + xk0] = xv0;
        *(short8*)&Alds[bb][xm1 * LROW + xk0] = xv1;
        if (t < 64) {
            unsigned short ev[4];
#pragma unroll
            for (int j = 0; j < 4; ++j) {
                float wj = wv[j];
                float e = (__builtin_fabsf(wj) * cv[j] > pthr) ? wj : 0.0f;
                ev[j] = f2bf(e);
            }
            ushort4v e4 = {ev[0], ev[1], ev[2], ev[3]};
            *(ushort4v*)&Blds[bb][(40 + w_o) * LROW + w_k] = e4;
        }
    };

    f32x4 acc[3];
#pragma unroll
    for (int n = 0; n < 3; ++n) acc[n] = (f32x4){0.f, 0.f, 0.f, 0.f};

    auto compute = [&](int bb) {
        const unsigned short* Ap = &Alds[bb][(wave * 16 + l15) * LROW + q * 8];
        const unsigned short* Bp = &Blds[bb][l15 * LROW + q * 8];
#pragma unroll
        for (int ks = 0; ks < KT; ks += 32) {
            short8 a  = *(const short8*)(Ap + ks);
            short8 b0 = *(const short8*)(Bp + ks);
            short8 b1 = *(const short8*)(Bp + 16 * LROW + ks);
            short8 b2 = *(const short8*)(Bp + 32 * LROW + ks);
            acc[0] = __builtin_amdgcn_mfma_f32_16x16x32_bf16(a, b0, acc[0], 0, 0, 0);
            acc[1] = __builtin_amdgcn_mfma_f32_16x16x32_bf16(a, b1, acc[1], 0, 0, 0);
            acc[2] = __builtin_amdgcn_mfma_f32_16x16x32_bf16(a, b2, acc[2], 0, 0, 0);
        }
    };

    // ---- double-buffered K loop ----
    load_stage(0);
    store_stage(0);
    __syncthreads();
    int bb = 0;
    for (int it = 1; it < NSTAGE; ++it) {
        load_stage(it * KT);          // issue next tile's global loads
        compute(bb);                  // MFMA on current tile
        store_stage(bb ^ 1);          // cvt + LDS write next tile
        __syncthreads();
        bb ^= 1;
    }
    compute(bb);

    // ---- epilogue ----
    // D[m][n]: m = wave*16 + q*4 + r, n = nt*16 + l15
    const int brow = wave * 16 + q * 4;
#pragma unroll
    for (int nt = 0; nt < 3; ++nt) {
        const int n = nt * 16 + l15;
        if (n < 40) {
            const int ol = n / 10;
            const int s = n - ol * 10;
            const float g = 1.0f / (1.0f + expf(-gates[(o0 + ol) * Sn + s]));
#pragma unroll
            for (int r = 0; r < 4; ++r) {
                float v = acc[nt][r];
                v = v > 0.0f ? v : 0.0f;
                atomicAdd(&dsum[brow + r][ol], v * g);
            }
        } else if (n < 44) {
            const int ol = n - 40;
#pragma unroll
            for (int r = 0; r < 4; ++r) ssum[brow + r][ol] = acc[nt][r];
        }
    }
    __syncthreads();
    {
        const int m = t >> 2;
        const int ol = t & 3;
        const int o = o0 + ol;
        float v = dsum[m][ol] + mastro[ol] * ssum[m][ol] + bias[o];
        out[(size_t)m * On + o] = v > 0.0f ? v : 0.0f;
    }
}

extern "C" void kernel_launch(void* const* d_in, const int* in_sizes, int n_in,
                              void* d_out, int out_size, void* d_ws, size_t ws_size,
                              hipStream_t stream) {
    (void)in_sizes; (void)n_in; (void)out_size; (void)ws_size;
    const float* x    = (const float*)d_in[0];
    const float* ctx  = (const float*)d_in[1];
    // d_in[2] prev_activation: unused by the reference
    const float* wgt  = (const float*)d_in[3];
    const float* bias = (const float*)d_in[4];
    const float* aact = (const float*)d_in[5];
    const float* athr = (const float*)d_in[6];
    const float* seg  = (const float*)d_in[7];
    const float* gat  = (const float*)d_in[8];
    const float* cst  = (const float*)d_in[9];
    const float* prn  = (const float*)d_in[10];
    float* out = (float*)d_out;

    float* ws_ctx = (float*)d_ws;
    unsigned short* ws_xbf = (unsigned short*)((char*)d_ws + 256);

    prep_kernel<<<Bn + (Bn * In) / 256, 256, 0, stream>>>(x, ctx, ws_ctx, ws_xbf);
    main_kernel<<<On / OT, 256, 0, stream>>>(ws_xbf, wgt, cst, seg, bias, aact,
                                             athr, gat, prn, ws_ctx, out);
}